// Round 11
// baseline (339.956 us; speedup 1.0000x reference)
//
#include <hip/hip_runtime.h>

namespace {
constexpr int E_N  = 131072;
constexpr int FEA  = 256;
constexpr int RAD  = 64;
constexpr int HID  = 128;
constexpr int WN   = 256;
constexpr int EPB  = 64;    // edges per block
constexpr int NT   = 256;   // 4 waves
constexpr int ASTR = 132;   // act stride (floats), 16B-aligned rows
constexpr int SMEMF = EPB * ASTR;   // 8448 floats = 33792 B time-aliased
}

typedef float float2v __attribute__((ext_vector_type(2)));

// VOP3P packed FMA, src0 word-broadcast via op_sel:
//   lo-bcast: d = {s0.x*s1.x + c.x, s0.x*s1.y + c.y}
__device__ __forceinline__ float2v pkfma_lo(float2v a, float2v b, float2v c) {
    float2v d;
    asm("v_pk_fma_f32 %0, %1, %2, %3 op_sel:[0,0,0] op_sel_hi:[0,1,1]"
        : "=v"(d) : "v"(a), "v"(b), "v"(c));
    return d;
}
//   hi-bcast: d = {s0.y*s1.x + c.x, s0.y*s1.y + c.y}
__device__ __forceinline__ float2v pkfma_hi(float2v a, float2v b, float2v c) {
    float2v d;
    asm("v_pk_fma_f32 %0, %1, %2, %3 op_sel:[1,0,0] op_sel_hi:[1,1,1]"
        : "=v"(d) : "v"(a), "v"(b), "v"(c));
    return d;
}

__global__ __launch_bounds__(NT, 4)
void fused_mlp_dtp(
    const float* __restrict__ fea_a, const float* __restrict__ vec_a,
    const float* __restrict__ len_a, const float* __restrict__ W1_a,
    const float* __restrict__ b1_a,  const float* __restrict__ g_a,
    const float* __restrict__ be_a,  const float* __restrict__ W2_a,
    const float* __restrict__ fea_b, const float* __restrict__ vec_b,
    const float* __restrict__ len_b, const float* __restrict__ W1_b,
    const float* __restrict__ b1_b,  const float* __restrict__ g_b,
    const float* __restrict__ be_b,  const float* __restrict__ W2_b,
    float* __restrict__ out)
{
    // Time-aliased LDS (33792 B):
    //   phases 1-2:  len f32[64][64] in [0,16K)
    //   phases 2b-4: act f32[64][132]
    //   epilogue:    stage 4 x 1536 f32 in [0,24.6K)
    __shared__ __align__(16) float smem[SMEMF];

    const int pipe = blockIdx.y;
    const float* __restrict__ fea = pipe ? fea_b : fea_a;
    const float* __restrict__ vec = pipe ? vec_b : vec_a;
    const float* __restrict__ len = pipe ? len_b : len_a;
    const float* __restrict__ W1  = pipe ? W1_b  : W1_a;
    const float* __restrict__ b1  = pipe ? b1_b  : b1_a;
    const float* __restrict__ g   = pipe ? g_b   : g_a;
    const float* __restrict__ be  = pipe ? be_b  : be_a;
    const float* __restrict__ W2  = pipe ? W2_b  : W2_a;
    float* __restrict__ outp = out + (size_t)pipe * (size_t)E_N * FEA;

    const int t    = threadIdx.x;
    const int lane = t & 63;
    const int wv_  = t >> 6;
    const long e0  = (long)blockIdx.x * EPB;

    // ---------- Phase 1: stage len tile [64][64] ----------
    {
        const float4* __restrict__ src = (const float4*)(len + e0 * RAD);
        float4* dst = (float4*)smem;
        #pragma unroll
        for (int i = 0; i < (EPB * RAD / 4) / NT; ++i)
            dst[t + i * NT] = src[t + i * NT];
    }
    __syncthreads();

    // ---------- Phase 2: h = len @ W1 + b1, acc in regs (comp-pairs) --------
    const int c0 = (t & 31) * 4;        // col block 0..124
    const int eb = (t >> 5) * 8;        // edge block 0..56
    float2v accA[8], accB[8];           // cols (c0,c0+1) and (c0+2,c0+3)
    {
        #pragma unroll
        for (int i = 0; i < 8; ++i) { accA[i] = (float2v)0.f; accB[i] = (float2v)0.f; }

        for (int kg = 0; kg < RAD / 4; ++kg) {
            float4 w0 = *(const float4*)(W1 + (size_t)(kg*4 + 0) * HID + c0);
            float4 w1 = *(const float4*)(W1 + (size_t)(kg*4 + 1) * HID + c0);
            float4 w2 = *(const float4*)(W1 + (size_t)(kg*4 + 2) * HID + c0);
            float4 w3 = *(const float4*)(W1 + (size_t)(kg*4 + 3) * HID + c0);
            const float2v w0A = *(float2v*)&w0, w0B = *((float2v*)&w0 + 1);
            const float2v w1A = *(float2v*)&w1, w1B = *((float2v*)&w1 + 1);
            const float2v w2A = *(float2v*)&w2, w2B = *((float2v*)&w2 + 1);
            const float2v w3A = *(float2v*)&w3, w3B = *((float2v*)&w3 + 1);
            #pragma unroll
            for (int i = 0; i < 8; ++i) {
                float4 lv = *(const float4*)(&smem[(eb + i) * RAD + kg * 4]);
                const float2v lvA = *(float2v*)&lv;        // {k0, k1}
                const float2v lvB = *((float2v*)&lv + 1);  // {k2, k3}
                accA[i] = pkfma_lo(lvA, w0A, accA[i]);     // k0
                accB[i] = pkfma_lo(lvA, w0B, accB[i]);
                accA[i] = pkfma_hi(lvA, w1A, accA[i]);     // k1
                accB[i] = pkfma_hi(lvA, w1B, accB[i]);
                accA[i] = pkfma_lo(lvB, w2A, accA[i]);     // k2
                accB[i] = pkfma_lo(lvB, w2B, accB[i]);
                accA[i] = pkfma_hi(lvB, w3A, accA[i]);     // k3
                accB[i] = pkfma_hi(lvB, w3B, accB[i]);
            }
        }
    }
    __syncthreads();   // len reads complete; region becomes act

    // ---------- Phase 2b: write h into act[64][132] ----------
    {
        const float4 bv = *(const float4*)(b1 + c0);
        #pragma unroll
        for (int i = 0; i < 8; ++i) {
            const float4 o = make_float4(accA[i].x + bv.x, accA[i].y + bv.y,
                                         accB[i].x + bv.z, accB[i].y + bv.w);
            *(float4*)(&smem[(eb + i) * ASTR + c0]) = o;
        }
    }
    __syncthreads();

    // ---------- Phase 3: LayerNorm + SiLU in place ----------
    {
        const int e = t >> 2;               // 0..63
        const int q = t & 3;                // 4 threads/edge, 32 cols each
        float* __restrict__ row = &smem[e * ASTR + q * 32];
        float hv[32];
        float s = 0.f, s2 = 0.f;
        #pragma unroll
        for (int j = 0; j < 8; ++j) {
            const float4 v = *(const float4*)(row + 4 * j);
            hv[4*j+0] = v.x; hv[4*j+1] = v.y; hv[4*j+2] = v.z; hv[4*j+3] = v.w;
            s  += v.x + v.y + v.z + v.w;
            s2 += v.x*v.x + v.y*v.y + v.z*v.z + v.w*v.w;
        }
        s  += __shfl_xor(s, 1);  s  += __shfl_xor(s, 2);
        s2 += __shfl_xor(s2, 1); s2 += __shfl_xor(s2, 2);
        const float mu  = s * (1.0f / HID);
        float var = s2 * (1.0f / HID) - mu * mu;
        var = fmaxf(var, 0.0f);
        const float inv = rsqrtf(var + 1e-5f);
        const float4* __restrict__ gr  = (const float4*)(g  + q * 32);
        const float4* __restrict__ ber = (const float4*)(be + q * 32);
        #pragma unroll
        for (int j = 0; j < 8; ++j) {
            const float4 gv = gr[j];
            const float4 bv = ber[j];
            const float h0 = (hv[4*j+0] - mu) * inv * gv.x + bv.x;
            const float h1 = (hv[4*j+1] - mu) * inv * gv.y + bv.y;
            const float h2 = (hv[4*j+2] - mu) * inv * gv.z + bv.z;
            const float h3 = (hv[4*j+3] - mu) * inv * gv.w + bv.w;
            float4 o;
            o.x = h0 / (1.0f + __expf(-h0));
            o.y = h1 / (1.0f + __expf(-h1));
            o.z = h2 / (1.0f + __expf(-h2));
            o.w = h3 / (1.0f + __expf(-h3));
            *(float4*)(row + 4 * j) = o;
        }
    }
    __syncthreads();

    // ---------- Phase 4: w = silu @ W2, TWO 8-edge passes (32 hot acc) ------
    const int u   = lane;
    const int eb4 = wv_ * 16;

    // Pass A: edges eb4+0 .. eb4+7
    float2v a01A[8], a23A[8];
    #pragma unroll
    for (int i = 0; i < 8; ++i) { a01A[i] = (float2v)0.f; a23A[i] = (float2v)0.f; }
    for (int kg = 0; kg < HID / 4; ++kg) {
        const float* __restrict__ Wb = W2 + (size_t)(kg * 4) * WN + u;
        float2v p01[4], p23[4];
        #pragma unroll
        for (int kk = 0; kk < 4; ++kk) {
            p01[kk].x = Wb[kk * WN];
            p01[kk].y = Wb[kk * WN + 64];
            p23[kk].x = Wb[kk * WN + 128];
            p23[kk].y = Wb[kk * WN + 192];
        }
        #pragma unroll
        for (int i = 0; i < 8; ++i) {
            float4 av = *(const float4*)(&smem[(eb4 + i) * ASTR + kg * 4]);
            const float2v avA = *(float2v*)&av;        // {k0, k1}
            const float2v avB = *((float2v*)&av + 1);  // {k2, k3}
            a01A[i] = pkfma_lo(avA, p01[0], a01A[i]);
            a23A[i] = pkfma_lo(avA, p23[0], a23A[i]);
            a01A[i] = pkfma_hi(avA, p01[1], a01A[i]);
            a23A[i] = pkfma_hi(avA, p23[1], a23A[i]);
            a01A[i] = pkfma_lo(avB, p01[2], a01A[i]);
            a23A[i] = pkfma_lo(avB, p23[2], a23A[i]);
            a01A[i] = pkfma_hi(avB, p01[3], a01A[i]);
            a23A[i] = pkfma_hi(avB, p23[3], a23A[i]);
        }
    }

    // Pass B: edges eb4+8 .. eb4+15 (A results are cold; may park in AGPR)
    float2v a01B[8], a23B[8];
    #pragma unroll
    for (int i = 0; i < 8; ++i) { a01B[i] = (float2v)0.f; a23B[i] = (float2v)0.f; }
    for (int kg = 0; kg < HID / 4; ++kg) {
        const float* __restrict__ Wb = W2 + (size_t)(kg * 4) * WN + u;
        float2v p01[4], p23[4];
        #pragma unroll
        for (int kk = 0; kk < 4; ++kk) {
            p01[kk].x = Wb[kk * WN];
            p01[kk].y = Wb[kk * WN + 64];
            p23[kk].x = Wb[kk * WN + 128];
            p23[kk].y = Wb[kk * WN + 192];
        }
        #pragma unroll
        for (int i = 0; i < 8; ++i) {
            float4 av = *(const float4*)(&smem[(eb4 + 8 + i) * ASTR + kg * 4]);
            const float2v avA = *(float2v*)&av;
            const float2v avB = *((float2v*)&av + 1);
            a01B[i] = pkfma_lo(avA, p01[0], a01B[i]);
            a23B[i] = pkfma_lo(avA, p23[0], a23B[i]);
            a01B[i] = pkfma_hi(avA, p01[1], a01B[i]);
            a23B[i] = pkfma_hi(avA, p23[1], a23B[i]);
            a01B[i] = pkfma_lo(avB, p01[2], a01B[i]);
            a23B[i] = pkfma_lo(avB, p23[2], a23B[i]);
            a01B[i] = pkfma_hi(avB, p01[3], a01B[i]);
            a23B[i] = pkfma_hi(avB, p23[3], a23B[i]);
        }
    }
    __syncthreads();   // act reads done; region becomes epilogue stage

    // ---------- Epilogue: DTP per 8-edge chunk; out0 direct, out1 staged ----
    const float c2 = 0.70710678118654752f;   // 1/sqrt(2)
    const float c3 = 0.40824829046386302f;   // 1/sqrt(6)
    float* sStage = smem + wv_ * 1536;       // 6 KB per wave, disjoint

    // ---- chunk A (edges eb4+0..7) ----
    {
        const long eb8 = e0 + eb4;
        #pragma unroll
        for (int m = 0; m < 8; ++m) {
            const long e = eb8 + m;
            const float4 y = *(const float4*)(vec + e * 4);
            const float* __restrict__ fr = fea + e * (size_t)FEA;
            const float x0  = fr[u];
            const float x1a = fr[64 + 3*u + 0];
            const float x1b = fr[64 + 3*u + 1];
            const float x1c = fr[64 + 3*u + 2];
            const float w1 = a01A[m].x, w2 = a01A[m].y;
            const float w3 = a23A[m].x, w4 = a23A[m].y;
            const float dot = x1a*y.y + x1b*y.z + x1c*y.w;
            outp[e * (size_t)FEA + u] = w1*x0*y.x*c2 + w4*dot*c3;  // 256B/instr
            sStage[m*192 + 3*u + 0] = (w2*x0*y.y + w3*x1a*y.x) * c2;
            sStage[m*192 + 3*u + 1] = (w2*x0*y.z + w3*x1b*y.x) * c2;
            sStage[m*192 + 3*u + 2] = (w2*x0*y.w + w3*x1c*y.x) * c2;
        }
        __syncthreads();   // stage complete (convergent)
        #pragma unroll
        for (int rr = 0; rr < 6; ++rr) {
            const int flat = rr * 256 + u * 4;   // 0..1532, 16B aligned
            const int eloc = flat / 192;         // 0..7
            const int pos  = flat % 192;
            const float4 v = *(const float4*)(&sStage[flat]);
            *(float4*)(&outp[(eb8 + eloc) * (size_t)FEA + 64 + pos]) = v;
        }
        __syncthreads();   // drain complete before chunk B overwrites
    }
    // ---- chunk B (edges eb4+8..15) ----
    {
        const long eb8 = e0 + eb4 + 8;
        #pragma unroll
        for (int m = 0; m < 8; ++m) {
            const long e = eb8 + m;
            const float4 y = *(const float4*)(vec + e * 4);
            const float* __restrict__ fr = fea + e * (size_t)FEA;
            const float x0  = fr[u];
            const float x1a = fr[64 + 3*u + 0];
            const float x1b = fr[64 + 3*u + 1];
            const float x1c = fr[64 + 3*u + 2];
            const float w1 = a01B[m].x, w2 = a01B[m].y;
            const float w3 = a23B[m].x, w4 = a23B[m].y;
            const float dot = x1a*y.y + x1b*y.z + x1c*y.w;
            outp[e * (size_t)FEA + u] = w1*x0*y.x*c2 + w4*dot*c3;
            sStage[m*192 + 3*u + 0] = (w2*x0*y.y + w3*x1a*y.x) * c2;
            sStage[m*192 + 3*u + 1] = (w2*x0*y.z + w3*x1b*y.x) * c2;
            sStage[m*192 + 3*u + 2] = (w2*x0*y.w + w3*x1c*y.x) * c2;
        }
        __syncthreads();
        #pragma unroll
        for (int rr = 0; rr < 6; ++rr) {
            const int flat = rr * 256 + u * 4;
            const int eloc = flat / 192;
            const int pos  = flat % 192;
            const float4 v = *(const float4*)(&sStage[flat]);
            *(float4*)(&outp[(eb8 + eloc) * (size_t)FEA + 64 + pos]) = v;
        }
    }
}

extern "C" void kernel_launch(void* const* d_in, const int* in_sizes, int n_in,
                              void* d_out, int out_size, void* d_ws, size_t ws_size,
                              hipStream_t stream) {
    (void)in_sizes; (void)n_in; (void)d_ws; (void)ws_size; (void)out_size;
    const float* fea_a = (const float*)d_in[0];
    const float* vec_a = (const float*)d_in[1];
    const float* len_a = (const float*)d_in[2];
    const float* W1_a  = (const float*)d_in[3];
    const float* b1_a  = (const float*)d_in[4];
    const float* g_a   = (const float*)d_in[5];
    const float* be_a  = (const float*)d_in[6];
    const float* W2_a  = (const float*)d_in[7];
    const float* fea_b = (const float*)d_in[8];
    const float* vec_b = (const float*)d_in[9];
    const float* len_b = (const float*)d_in[10];
    const float* W1_b  = (const float*)d_in[11];
    const float* b1_b  = (const float*)d_in[12];
    const float* g_b   = (const float*)d_in[13];
    const float* be_b  = (const float*)d_in[14];
    const float* W2_b  = (const float*)d_in[15];
    float* out = (float*)d_out;

    dim3 grid(E_N / EPB, 2);
    dim3 block(NT);
    hipLaunchKernelGGL(fused_mlp_dtp, grid, block, 0, stream,
                       fea_a, vec_a, len_a, W1_a, b1_a, g_a, be_a, W2_a,
                       fea_b, vec_b, len_b, W1_b, b1_b, g_b, be_b, W2_b,
                       out);
}

// Round 12
// 322.744 us; speedup vs baseline: 1.0533x; 1.0533x over previous
//
#include <hip/hip_runtime.h>

namespace {
constexpr int E_N  = 131072;
constexpr int FEA  = 256;
constexpr int RAD  = 64;
constexpr int HID  = 128;
constexpr int WN   = 256;
constexpr int EPB  = 64;    // edges per block
constexpr int NT   = 256;   // 4 waves
constexpr int ASTR = 132;   // act stride (floats), 16B-aligned rows
constexpr int SMEMF = EPB * ASTR;   // 8448 floats = 33792 B time-aliased
}

typedef float float2v __attribute__((ext_vector_type(2)));

// VOP3P packed FMA, src0 word-broadcast via op_sel:
//   lo-bcast: d = {s0.x*s1.x + c.x, s0.x*s1.y + c.y}
__device__ __forceinline__ float2v pkfma_lo(float2v a, float2v b, float2v c) {
    float2v d;
    asm("v_pk_fma_f32 %0, %1, %2, %3 op_sel:[0,0,0] op_sel_hi:[0,1,1]"
        : "=v"(d) : "v"(a), "v"(b), "v"(c));
    return d;
}
//   hi-bcast: d = {s0.y*s1.x + c.x, s0.y*s1.y + c.y}
__device__ __forceinline__ float2v pkfma_hi(float2v a, float2v b, float2v c) {
    float2v d;
    asm("v_pk_fma_f32 %0, %1, %2, %3 op_sel:[1,0,0] op_sel_hi:[1,1,1]"
        : "=v"(d) : "v"(a), "v"(b), "v"(c));
    return d;
}

__global__
__attribute__((amdgpu_flat_work_group_size(256, 256), amdgpu_waves_per_eu(4, 4)))
void fused_mlp_dtp(
    const float* __restrict__ fea_a, const float* __restrict__ vec_a,
    const float* __restrict__ len_a, const float* __restrict__ W1_a,
    const float* __restrict__ b1_a,  const float* __restrict__ g_a,
    const float* __restrict__ be_a,  const float* __restrict__ W2_a,
    const float* __restrict__ fea_b, const float* __restrict__ vec_b,
    const float* __restrict__ len_b, const float* __restrict__ W1_b,
    const float* __restrict__ b1_b,  const float* __restrict__ g_b,
    const float* __restrict__ be_b,  const float* __restrict__ W2_b,
    float* __restrict__ out)
{
    // Time-aliased LDS (33792 B):
    //   phases 1-2:  len f32[64][64] in [0,16K)
    //   phases 2b-4: act f32[64][132]
    //   epilogue:    stage 4 x 768 f32 in [0,12K)
    __shared__ __align__(16) float smem[SMEMF];

    const int pipe = blockIdx.y;
    const float* __restrict__ fea = pipe ? fea_b : fea_a;
    const float* __restrict__ vec = pipe ? vec_b : vec_a;
    const float* __restrict__ len = pipe ? len_b : len_a;
    const float* __restrict__ W1  = pipe ? W1_b  : W1_a;
    const float* __restrict__ b1  = pipe ? b1_b  : b1_a;
    const float* __restrict__ g   = pipe ? g_b   : g_a;
    const float* __restrict__ be  = pipe ? be_b  : be_a;
    const float* __restrict__ W2  = pipe ? W2_b  : W2_a;
    float* __restrict__ outp = out + (size_t)pipe * (size_t)E_N * FEA;

    const int t    = threadIdx.x;
    const int lane = t & 63;
    const int wv_  = t >> 6;
    const long e0  = (long)blockIdx.x * EPB;

    // ---------- Phase 1: stage len tile [64][64] ----------
    {
        const float4* __restrict__ src = (const float4*)(len + e0 * RAD);
        float4* dst = (float4*)smem;
        #pragma unroll
        for (int i = 0; i < (EPB * RAD / 4) / NT; ++i)
            dst[t + i * NT] = src[t + i * NT];
    }
    __syncthreads();

    // ---------- Phase 2: h = len @ W1 + b1, acc in regs (comp-pairs) --------
    const int c0 = (t & 31) * 4;        // col block 0..124
    const int eb = (t >> 5) * 8;        // edge block 0..56
    float2v accA[8], accB[8];           // cols (c0,c0+1) and (c0+2,c0+3)
    {
        #pragma unroll
        for (int i = 0; i < 8; ++i) { accA[i] = (float2v)0.f; accB[i] = (float2v)0.f; }

        for (int kg = 0; kg < RAD / 4; ++kg) {
            float4 w0 = *(const float4*)(W1 + (size_t)(kg*4 + 0) * HID + c0);
            float4 w1 = *(const float4*)(W1 + (size_t)(kg*4 + 1) * HID + c0);
            float4 w2 = *(const float4*)(W1 + (size_t)(kg*4 + 2) * HID + c0);
            float4 w3 = *(const float4*)(W1 + (size_t)(kg*4 + 3) * HID + c0);
            const float2v w0A = *(float2v*)&w0, w0B = *((float2v*)&w0 + 1);
            const float2v w1A = *(float2v*)&w1, w1B = *((float2v*)&w1 + 1);
            const float2v w2A = *(float2v*)&w2, w2B = *((float2v*)&w2 + 1);
            const float2v w3A = *(float2v*)&w3, w3B = *((float2v*)&w3 + 1);
            #pragma unroll
            for (int i = 0; i < 8; ++i) {
                float4 lv = *(const float4*)(&smem[(eb + i) * RAD + kg * 4]);
                const float2v lvA = *(float2v*)&lv;        // {k0, k1}
                const float2v lvB = *((float2v*)&lv + 1);  // {k2, k3}
                accA[i] = pkfma_lo(lvA, w0A, accA[i]);     // k0
                accB[i] = pkfma_lo(lvA, w0B, accB[i]);
                accA[i] = pkfma_hi(lvA, w1A, accA[i]);     // k1
                accB[i] = pkfma_hi(lvA, w1B, accB[i]);
                accA[i] = pkfma_lo(lvB, w2A, accA[i]);     // k2
                accB[i] = pkfma_lo(lvB, w2B, accB[i]);
                accA[i] = pkfma_hi(lvB, w3A, accA[i]);     // k3
                accB[i] = pkfma_hi(lvB, w3B, accB[i]);
            }
        }
    }
    __syncthreads();   // len reads complete; region becomes act

    // ---------- Phase 2b: write h into act[64][132] ----------
    {
        const float4 bv = *(const float4*)(b1 + c0);
        #pragma unroll
        for (int i = 0; i < 8; ++i) {
            const float4 o = make_float4(accA[i].x + bv.x, accA[i].y + bv.y,
                                         accB[i].x + bv.z, accB[i].y + bv.w);
            *(float4*)(&smem[(eb + i) * ASTR + c0]) = o;
        }
    }
    __syncthreads();

    // ---------- Phase 3: LayerNorm + SiLU in place ----------
    {
        const int e = t >> 2;               // 0..63
        const int q = t & 3;                // 4 threads/edge, 32 cols each
        float* __restrict__ row = &smem[e * ASTR + q * 32];
        float hv[32];
        float s = 0.f, s2 = 0.f;
        #pragma unroll
        for (int j = 0; j < 8; ++j) {
            const float4 v = *(const float4*)(row + 4 * j);
            hv[4*j+0] = v.x; hv[4*j+1] = v.y; hv[4*j+2] = v.z; hv[4*j+3] = v.w;
            s  += v.x + v.y + v.z + v.w;
            s2 += v.x*v.x + v.y*v.y + v.z*v.z + v.w*v.w;
        }
        s  += __shfl_xor(s, 1);  s  += __shfl_xor(s, 2);
        s2 += __shfl_xor(s2, 1); s2 += __shfl_xor(s2, 2);
        const float mu  = s * (1.0f / HID);
        float var = s2 * (1.0f / HID) - mu * mu;
        var = fmaxf(var, 0.0f);
        const float inv = rsqrtf(var + 1e-5f);
        const float4* __restrict__ gr  = (const float4*)(g  + q * 32);
        const float4* __restrict__ ber = (const float4*)(be + q * 32);
        #pragma unroll
        for (int j = 0; j < 8; ++j) {
            const float4 gv = gr[j];
            const float4 bv = ber[j];
            const float h0 = (hv[4*j+0] - mu) * inv * gv.x + bv.x;
            const float h1 = (hv[4*j+1] - mu) * inv * gv.y + bv.y;
            const float h2 = (hv[4*j+2] - mu) * inv * gv.z + bv.z;
            const float h3 = (hv[4*j+3] - mu) * inv * gv.w + bv.w;
            float4 o;
            o.x = h0 / (1.0f + __expf(-h0));
            o.y = h1 / (1.0f + __expf(-h1));
            o.z = h2 / (1.0f + __expf(-h2));
            o.w = h3 / (1.0f + __expf(-h3));
            *(float4*)(row + 4 * j) = o;
        }
    }
    __syncthreads();

    // ---------- Phase 4: w = silu @ W2 (comp-pair op_sel pk-FMA) ----------
    const int u   = lane;
    const int eb4 = wv_ * 16;
    float2v a01[16], a23[16];   // {comp0,comp1} and {comp2,comp3} per edge
    {
        #pragma unroll
        for (int i = 0; i < 16; ++i) { a01[i] = (float2v)0.f; a23[i] = (float2v)0.f; }

        for (int kg = 0; kg < HID / 4; ++kg) {
            const float* __restrict__ Wb = W2 + (size_t)(kg * 4) * WN + u;
            float2v p01[4], p23[4];       // per kk: {W[k][u],W[k][64+u]}, {W[k][128+u],W[k][192+u]}
            #pragma unroll
            for (int kk = 0; kk < 4; ++kk) {
                p01[kk].x = Wb[kk * WN];
                p01[kk].y = Wb[kk * WN + 64];
                p23[kk].x = Wb[kk * WN + 128];
                p23[kk].y = Wb[kk * WN + 192];
            }
            #pragma unroll
            for (int i = 0; i < 16; ++i) {
                float4 av = *(const float4*)(&smem[(eb4 + i) * ASTR + kg * 4]);
                const float2v avA = *(float2v*)&av;        // {k0, k1}
                const float2v avB = *((float2v*)&av + 1);  // {k2, k3}
                a01[i] = pkfma_lo(avA, p01[0], a01[i]);    // k0
                a23[i] = pkfma_lo(avA, p23[0], a23[i]);
                a01[i] = pkfma_hi(avA, p01[1], a01[i]);    // k1
                a23[i] = pkfma_hi(avA, p23[1], a23[i]);
                a01[i] = pkfma_lo(avB, p01[2], a01[i]);    // k2
                a23[i] = pkfma_lo(avB, p23[2], a23[i]);
                a01[i] = pkfma_hi(avB, p01[3], a01[i]);    // k3
                a23[i] = pkfma_hi(avB, p23[3], a23[i]);
            }
        }
    }
    __syncthreads();   // act reads done; region becomes epilogue stage

    // ---------- Epilogue: DTP; out0 direct, out1 via barriered LDS stage ----
    {
        const long ebase = e0 + wv_ * 16;
        float* sStage = smem + wv_ * 768;            // 3 KB per wave, disjoint
        const float c2 = 0.70710678118654752f;       // 1/sqrt(2)
        const float c3 = 0.40824829046386302f;       // 1/sqrt(6)

        for (int ch = 0; ch < 4; ++ch) {
            #pragma unroll
            for (int m = 0; m < 4; ++m) {
                const int i = ch * 4 + m;
                const long e = ebase + i;
                const float4 y = *(const float4*)(vec + e * 4);
                const float* __restrict__ fr = fea + e * (size_t)FEA;
                const float x0  = fr[u];
                const float x1a = fr[64 + 3*u + 0];
                const float x1b = fr[64 + 3*u + 1];
                const float x1c = fr[64 + 3*u + 2];
                const float w1 = a01[i].x, w2 = a01[i].y;
                const float w3 = a23[i].x, w4 = a23[i].y;
                const float dot = x1a*y.y + x1b*y.z + x1c*y.w;
                outp[e * (size_t)FEA + u] = w1*x0*y.x*c2 + w4*dot*c3;  // 256B/instr
                sStage[m*192 + 3*u + 0] = (w2*x0*y.y + w3*x1a*y.x) * c2;
                sStage[m*192 + 3*u + 1] = (w2*x0*y.z + w3*x1b*y.x) * c2;
                sStage[m*192 + 3*u + 2] = (w2*x0*y.w + w3*x1c*y.x) * c2;
            }
            __syncthreads();   // stage complete (convergent: all waves, all ch)
            #pragma unroll
            for (int r = 0; r < 3; ++r) {
                const int flat = r * 256 + u * 4;    // 0..764, 16B aligned
                const int eloc = flat / 192;
                const int pos  = flat % 192;
                const float4 v = *(const float4*)(&sStage[flat]);
                *(float4*)(&outp[(ebase + ch*4 + eloc) * (size_t)FEA + 64 + pos]) = v;
            }
            __syncthreads();   // drain complete before next ch overwrites
        }
    }
}

extern "C" void kernel_launch(void* const* d_in, const int* in_sizes, int n_in,
                              void* d_out, int out_size, void* d_ws, size_t ws_size,
                              hipStream_t stream) {
    (void)in_sizes; (void)n_in; (void)d_ws; (void)ws_size; (void)out_size;
    const float* fea_a = (const float*)d_in[0];
    const float* vec_a = (const float*)d_in[1];
    const float* len_a = (const float*)d_in[2];
    const float* W1_a  = (const float*)d_in[3];
    const float* b1_a  = (const float*)d_in[4];
    const float* g_a   = (const float*)d_in[5];
    const float* be_a  = (const float*)d_in[6];
    const float* W2_a  = (const float*)d_in[7];
    const float* fea_b = (const float*)d_in[8];
    const float* vec_b = (const float*)d_in[9];
    const float* len_b = (const float*)d_in[10];
    const float* W1_b  = (const float*)d_in[11];
    const float* b1_b  = (const float*)d_in[12];
    const float* g_b   = (const float*)d_in[13];
    const float* be_b  = (const float*)d_in[14];
    const float* W2_b  = (const float*)d_in[15];
    float* out = (float*)d_out;

    dim3 grid(E_N / EPB, 2);
    dim3 block(NT);
    hipLaunchKernelGGL(fused_mlp_dtp, grid, block, 0, stream,
                       fea_a, vec_a, len_a, W1_a, b1_a, g_a, be_a, W2_a,
                       fea_b, vec_b, len_b, W1_b, b1_b, g_b, be_b, W2_b,
                       out);
}

// Round 13
// 219.523 us; speedup vs baseline: 1.5486x; 1.4702x over previous
//
#include <hip/hip_runtime.h>

namespace {
constexpr int E_N  = 131072;
constexpr int FEA  = 256;
constexpr int RAD  = 64;
constexpr int HID  = 128;
constexpr int WN   = 256;
constexpr int EPB  = 64;    // edges per block
constexpr int NT   = 256;   // 4 waves
constexpr int ASTR = 132;   // act stride (floats), 16B-aligned rows
constexpr int SMEMF = EPB * ASTR;        // 8448 floats = 33792 B time-aliased
constexpr int FRAG_HI_SHORTS = 2 * 4 * 16 * 64 * 8;  // 65536: hi block, both pipes
}

typedef float float2v __attribute__((ext_vector_type(2)));
typedef short short8v __attribute__((ext_vector_type(8)));   // 8 bf16 (4 VGPRs)
typedef float floatx4 __attribute__((ext_vector_type(4)));   // MFMA accumulator

__device__ __forceinline__ float2v pkfma_lo(float2v a, float2v b, float2v c) {
    float2v d;
    asm("v_pk_fma_f32 %0, %1, %2, %3 op_sel:[0,0,0] op_sel_hi:[0,1,1]"
        : "=v"(d) : "v"(a), "v"(b), "v"(c));
    return d;
}
__device__ __forceinline__ float2v pkfma_hi(float2v a, float2v b, float2v c) {
    float2v d;
    asm("v_pk_fma_f32 %0, %1, %2, %3 op_sel:[1,0,0] op_sel_hi:[1,1,1]"
        : "=v"(d) : "v"(a), "v"(b), "v"(c));
    return d;
}

__device__ __forceinline__ unsigned bf16rne(float x) {       // f32 -> bf16 (RNE)
    const unsigned u = __float_as_uint(x);
    return (u + 0x7FFFu + ((u >> 16) & 1u)) >> 16;
}
__device__ __forceinline__ float bf16tof(unsigned h) {
    return __uint_as_float(h << 16);
}
__device__ __forceinline__ void bf16split(float x, unsigned& hi, unsigned& lo) {
    hi = bf16rne(x);
    lo = bf16rne(x - bf16tof(hi));
}

union FragU { uint4 u; short8v v; };

// ---- Prep: split W2 (both pipes) into bf16 hi/lo MFMA B-fragments in d_ws ----
// Fragment convention (matches A): lane = s + 16*g holds k = 32*kt + 8*g + j,
// column nb*16 + s.  hi block: frag[pipe*32768 + ((kt*16+nb)*64+lane)*8 + j];
// lo block at +FRAG_HI_SHORTS.
__global__ __launch_bounds__(64)
void prep_w2(const float* __restrict__ W2a, const float* __restrict__ W2b,
             unsigned short* __restrict__ frag)
{
    const int lane = threadIdx.x;
    const int nb = blockIdx.x, kt = blockIdx.y, pipe = blockIdx.z;
    const float* __restrict__ W2 = pipe ? W2b : W2a;
    const int g = lane >> 4, s = lane & 15;
    unsigned ph[4], pl[4];
    #pragma unroll
    for (int p = 0; p < 4; ++p) {
        const float x0 = W2[(size_t)(32*kt + 8*g + 2*p)     * WN + nb*16 + s];
        const float x1 = W2[(size_t)(32*kt + 8*g + 2*p + 1) * WN + nb*16 + s];
        unsigned h0, l0, h1, l1;
        bf16split(x0, h0, l0);
        bf16split(x1, h1, l1);
        ph[p] = h0 | (h1 << 16);
        pl[p] = l0 | (l1 << 16);
    }
    const size_t fi = (size_t)pipe * 32768 + (size_t)((kt*16 + nb)*64 + lane) * 8;
    *(uint4*)(frag + fi)                  = make_uint4(ph[0], ph[1], ph[2], ph[3]);
    *(uint4*)(frag + FRAG_HI_SHORTS + fi) = make_uint4(pl[0], pl[1], pl[2], pl[3]);
}

__global__ __launch_bounds__(NT, 4)
void fused_mlp_dtp(
    const float* __restrict__ fea_a, const float* __restrict__ vec_a,
    const float* __restrict__ len_a, const float* __restrict__ W1_a,
    const float* __restrict__ b1_a,  const float* __restrict__ g_a,
    const float* __restrict__ be_a,  const float* __restrict__ W2_a,
    const float* __restrict__ fea_b, const float* __restrict__ vec_b,
    const float* __restrict__ len_b, const float* __restrict__ W1_b,
    const float* __restrict__ b1_b,  const float* __restrict__ g_b,
    const float* __restrict__ be_b,  const float* __restrict__ W2_b,
    const unsigned short* __restrict__ fragW,
    float* __restrict__ out)
{
    // Time-aliased LDS (33792 B): len [0,16K) -> act [0,33792) -> stage [0,12.6K)
    __shared__ __align__(16) float smem[SMEMF];

    const int pipe = blockIdx.y;
    const float* __restrict__ fea = pipe ? fea_b : fea_a;
    const float* __restrict__ vec = pipe ? vec_b : vec_a;
    const float* __restrict__ len = pipe ? len_b : len_a;
    const float* __restrict__ W1  = pipe ? W1_b  : W1_a;
    const float* __restrict__ b1  = pipe ? b1_b  : b1_a;
    const float* __restrict__ g   = pipe ? g_b   : g_a;
    const float* __restrict__ be  = pipe ? be_b  : be_a;
    float* __restrict__ outp = out + (size_t)pipe * (size_t)E_N * FEA;

    const int t    = threadIdx.x;
    const int lane = t & 63;
    const int wv_  = t >> 6;
    const long e0  = (long)blockIdx.x * EPB;

    // ---------- Phase 1: stage len tile [64][64] ----------
    {
        const float4* __restrict__ src = (const float4*)(len + e0 * RAD);
        float4* dst = (float4*)smem;
        #pragma unroll
        for (int i = 0; i < (EPB * RAD / 4) / NT; ++i)
            dst[t + i * NT] = src[t + i * NT];
    }
    __syncthreads();

    // ---------- Phase 2: h = len @ W1 + b1, acc in regs (op_sel pk-FMA) -----
    const int c0 = (t & 31) * 4;
    const int eb = (t >> 5) * 8;
    float2v accA[8], accB[8];
    {
        #pragma unroll
        for (int i = 0; i < 8; ++i) { accA[i] = (float2v)0.f; accB[i] = (float2v)0.f; }

        for (int kg = 0; kg < RAD / 4; ++kg) {
            float4 w0 = *(const float4*)(W1 + (size_t)(kg*4 + 0) * HID + c0);
            float4 w1 = *(const float4*)(W1 + (size_t)(kg*4 + 1) * HID + c0);
            float4 w2 = *(const float4*)(W1 + (size_t)(kg*4 + 2) * HID + c0);
            float4 w3 = *(const float4*)(W1 + (size_t)(kg*4 + 3) * HID + c0);
            const float2v w0A = *(float2v*)&w0, w0B = *((float2v*)&w0 + 1);
            const float2v w1A = *(float2v*)&w1, w1B = *((float2v*)&w1 + 1);
            const float2v w2A = *(float2v*)&w2, w2B = *((float2v*)&w2 + 1);
            const float2v w3A = *(float2v*)&w3, w3B = *((float2v*)&w3 + 1);
            #pragma unroll
            for (int i = 0; i < 8; ++i) {
                float4 lv = *(const float4*)(&smem[(eb + i) * RAD + kg * 4]);
                const float2v lvA = *(float2v*)&lv;
                const float2v lvB = *((float2v*)&lv + 1);
                accA[i] = pkfma_lo(lvA, w0A, accA[i]);
                accB[i] = pkfma_lo(lvA, w0B, accB[i]);
                accA[i] = pkfma_hi(lvA, w1A, accA[i]);
                accB[i] = pkfma_hi(lvA, w1B, accB[i]);
                accA[i] = pkfma_lo(lvB, w2A, accA[i]);
                accB[i] = pkfma_lo(lvB, w2B, accB[i]);
                accA[i] = pkfma_hi(lvB, w3A, accA[i]);
                accB[i] = pkfma_hi(lvB, w3B, accB[i]);
            }
        }
    }
    __syncthreads();   // len reads complete; region becomes act

    // ---------- Phase 2b: write h into act[64][132] ----------
    {
        const float4 bv = *(const float4*)(b1 + c0);
        #pragma unroll
        for (int i = 0; i < 8; ++i) {
            const float4 o = make_float4(accA[i].x + bv.x, accA[i].y + bv.y,
                                         accB[i].x + bv.z, accB[i].y + bv.w);
            *(float4*)(&smem[(eb + i) * ASTR + c0]) = o;
        }
    }
    __syncthreads();

    // ---------- Phase 3: LayerNorm + SiLU in place ----------
    {
        const int e = t >> 2;
        const int q = t & 3;
        float* __restrict__ row = &smem[e * ASTR + q * 32];
        float hv[32];
        float s = 0.f, s2 = 0.f;
        #pragma unroll
        for (int j = 0; j < 8; ++j) {
            const float4 v = *(const float4*)(row + 4 * j);
            hv[4*j+0] = v.x; hv[4*j+1] = v.y; hv[4*j+2] = v.z; hv[4*j+3] = v.w;
            s  += v.x + v.y + v.z + v.w;
            s2 += v.x*v.x + v.y*v.y + v.z*v.z + v.w*v.w;
        }
        s  += __shfl_xor(s, 1);  s  += __shfl_xor(s, 2);
        s2 += __shfl_xor(s2, 1); s2 += __shfl_xor(s2, 2);
        const float mu  = s * (1.0f / HID);
        float var = s2 * (1.0f / HID) - mu * mu;
        var = fmaxf(var, 0.0f);
        const float inv = rsqrtf(var + 1e-5f);
        const float4* __restrict__ gr  = (const float4*)(g  + q * 32);
        const float4* __restrict__ ber = (const float4*)(be + q * 32);
        #pragma unroll
        for (int j = 0; j < 8; ++j) {
            const float4 gv = gr[j];
            const float4 bv = ber[j];
            const float h0 = (hv[4*j+0] - mu) * inv * gv.x + bv.x;
            const float h1 = (hv[4*j+1] - mu) * inv * gv.y + bv.y;
            const float h2 = (hv[4*j+2] - mu) * inv * gv.z + bv.z;
            const float h3 = (hv[4*j+3] - mu) * inv * gv.w + bv.w;
            float4 o;
            o.x = h0 / (1.0f + __expf(-h0));
            o.y = h1 / (1.0f + __expf(-h1));
            o.z = h2 / (1.0f + __expf(-h2));
            o.w = h3 / (1.0f + __expf(-h3));
            *(float4*)(row + 4 * j) = o;
        }
    }
    __syncthreads();

    // ---------- Phase 4: w = silu @ W2 via split-bf16 MFMA (3 products) -----
    // Wave owns edges [16w,16w+16) = A rows; acc[nb] covers cols [16nb,16nb+16).
    // A split in registers from f32 act; B hi/lo loaded pre-split from fragW.
    const int s_ = lane & 15, g_ = lane >> 4;
    floatx4 acc[16];
    #pragma unroll
    for (int nb = 0; nb < 16; ++nb) {
        acc[nb][0] = 0.f; acc[nb][1] = 0.f; acc[nb][2] = 0.f; acc[nb][3] = 0.f;
    }
    {
        const int eA = wv_ * 16 + s_;        // A row supplied by this lane
        const unsigned short* __restrict__ fH = fragW + (size_t)pipe * 32768;
        const unsigned short* __restrict__ fL = fH + FRAG_HI_SHORTS;
        for (int kt = 0; kt < 4; ++kt) {
            float xs[8];
            {
                const float4 x0 = *(const float4*)(&smem[eA*ASTR + 32*kt + 8*g_]);
                const float4 x1 = *(const float4*)(&smem[eA*ASTR + 32*kt + 8*g_ + 4]);
                xs[0]=x0.x; xs[1]=x0.y; xs[2]=x0.z; xs[3]=x0.w;
                xs[4]=x1.x; xs[5]=x1.y; xs[6]=x1.z; xs[7]=x1.w;
            }
            FragU ahu, alu;
            {
                unsigned ph[4], pl[4];
                #pragma unroll
                for (int p = 0; p < 4; ++p) {
                    unsigned h0, l0, h1, l1;
                    bf16split(xs[2*p],     h0, l0);
                    bf16split(xs[2*p + 1], h1, l1);
                    ph[p] = h0 | (h1 << 16);
                    pl[p] = l0 | (l1 << 16);
                }
                ahu.u = make_uint4(ph[0], ph[1], ph[2], ph[3]);
                alu.u = make_uint4(pl[0], pl[1], pl[2], pl[3]);
            }
            const short8v ah = ahu.v, al = alu.v;
            const size_t kb = (size_t)(kt * 16) * 512 + (size_t)lane * 8;
            #pragma unroll
            for (int nb = 0; nb < 16; ++nb) {
                const short8v bh = *(const short8v*)(fH + kb + nb * 512);
                const short8v bl = *(const short8v*)(fL + kb + nb * 512);
                acc[nb] = __builtin_amdgcn_mfma_f32_16x16x32_bf16(ah, bh, acc[nb], 0, 0, 0);
                acc[nb] = __builtin_amdgcn_mfma_f32_16x16x32_bf16(ah, bl, acc[nb], 0, 0, 0);
                acc[nb] = __builtin_amdgcn_mfma_f32_16x16x32_bf16(al, bh, acc[nb], 0, 0, 0);
            }
        }
    }
    __syncthreads();   // all act reads done; region becomes epilogue stage

    // ---------- Epilogue: DTP from C-layout (col=lane&15, row=4*(lane>>4)+r)
    // Chunk by r: per chunk each lane handles edge 16w+4g_+r, u in {16q+s_}.
    {
        const float c2 = 0.70710678118654752f;   // 1/sqrt(2)
        const float c3 = 0.40824829046386302f;   // 1/sqrt(6)
        float* sStage = smem + wv_ * 784;        // [4 rows][196], per-wave
        for (int r = 0; r < 4; ++r) {
            const long e = e0 + wv_ * 16 + 4 * g_ + r;
            const float4 y = *(const float4*)(vec + e * 4);
            const float* __restrict__ fr   = fea  + e * (size_t)FEA;
            float* __restrict__       orow = outp + e * (size_t)FEA;
            #pragma unroll
            for (int q = 0; q < 4; ++q) {
                const int u = 16 * q + s_;
                const float w1 = acc[q     ][r];
                const float w2 = acc[q + 4 ][r];
                const float w3 = acc[q + 8 ][r];
                const float w4 = acc[q + 12][r];
                const float x0  = fr[u];
                const float x1a = fr[64 + 3*u + 0];
                const float x1b = fr[64 + 3*u + 1];
                const float x1c = fr[64 + 3*u + 2];
                const float dot = x1a*y.y + x1b*y.z + x1c*y.w;
                orow[u] = w1*x0*y.x*c2 + w4*dot*c3;       // 4 x 64B full sectors
                sStage[g_*196 + 3*u + 0] = (w2*x0*y.y + w3*x1a*y.x) * c2;
                sStage[g_*196 + 3*u + 1] = (w2*x0*y.z + w3*x1b*y.x) * c2;
                sStage[g_*196 + 3*u + 2] = (w2*x0*y.w + w3*x1c*y.x) * c2;
            }
            __syncthreads();   // stage complete (convergent: all waves, all r)
            #pragma unroll
            for (int rr = 0; rr < 3; ++rr) {
                const int flat = rr * 256 + lane * 4;     // 0..764
                const int eloc = flat / 192;              // 0..3 (g-group)
                const int pos  = flat % 192;              // 16B aligned
                const float4 v = *(const float4*)(&sStage[eloc * 196 + pos]);
                *(float4*)(&outp[(e0 + wv_*16 + 4*eloc + r) * (size_t)FEA + 64 + pos]) = v;
            }
            __syncthreads();   // drain complete before next r overwrites
        }
    }
}

extern "C" void kernel_launch(void* const* d_in, const int* in_sizes, int n_in,
                              void* d_out, int out_size, void* d_ws, size_t ws_size,
                              hipStream_t stream) {
    (void)in_sizes; (void)n_in; (void)ws_size; (void)out_size;
    const float* fea_a = (const float*)d_in[0];
    const float* vec_a = (const float*)d_in[1];
    const float* len_a = (const float*)d_in[2];
    const float* W1_a  = (const float*)d_in[3];
    const float* b1_a  = (const float*)d_in[4];
    const float* g_a   = (const float*)d_in[5];
    const float* be_a  = (const float*)d_in[6];
    const float* W2_a  = (const float*)d_in[7];
    const float* fea_b = (const float*)d_in[8];
    const float* vec_b = (const float*)d_in[9];
    const float* len_b = (const float*)d_in[10];
    const float* W1_b  = (const float*)d_in[11];
    const float* b1_b  = (const float*)d_in[12];
    const float* g_b   = (const float*)d_in[13];
    const float* be_b  = (const float*)d_in[14];
    const float* W2_b  = (const float*)d_in[15];
    float* out = (float*)d_out;
    unsigned short* frag = (unsigned short*)d_ws;   // needs 256 KB

    hipLaunchKernelGGL(prep_w2, dim3(16, 4, 2), dim3(64), 0, stream,
                       W2_a, W2_b, frag);

    dim3 grid(E_N / EPB, 2);
    dim3 block(NT);
    hipLaunchKernelGGL(fused_mlp_dtp, grid, block, 0, stream,
                       fea_a, vec_a, len_a, W1_a, b1_a, g_a, be_a, W2_a,
                       fea_b, vec_b, len_b, W1_b, b1_b, g_b, be_b, W2_b,
                       frag, out);
}

// Round 14
// 180.653 us; speedup vs baseline: 1.8818x; 1.2152x over previous
//
#include <hip/hip_runtime.h>

namespace {
constexpr int E_N  = 131072;
constexpr int FEA  = 256;
constexpr int RAD  = 64;
constexpr int HID  = 128;
constexpr int WN   = 256;
constexpr int EPB  = 64;    // edges per block
constexpr int NT   = 256;   // 4 waves
constexpr int LSTR = 68;    // len tile stride (floats), 16B-aligned
constexpr int ASTR = 132;   // act stride (floats), 16B-aligned rows
constexpr int SMEMF = EPB * ASTR;        // 8448 floats = 33792 B time-aliased
constexpr int FRAG_HI_SHORTS = 2 * 4 * 16 * 64 * 8;  // 65536: W2 hi, both pipes
constexpr int W1HI = 2 * FRAG_HI_SHORTS;             // 131072: W1 hi base
constexpr int W1LO_DELTA = 2 * 2 * 8 * 64 * 8;       // 16384 shorts
}

typedef short short8v __attribute__((ext_vector_type(8)));   // 8 bf16 (4 VGPRs)
typedef float floatx4 __attribute__((ext_vector_type(4)));   // MFMA accumulator

__device__ __forceinline__ unsigned bf16rne(float x) {       // f32 -> bf16 (RNE)
    const unsigned u = __float_as_uint(x);
    return (u + 0x7FFFu + ((u >> 16) & 1u)) >> 16;
}
__device__ __forceinline__ float bf16tof(unsigned h) {
    return __uint_as_float(h << 16);
}
__device__ __forceinline__ void bf16split(float x, unsigned& hi, unsigned& lo) {
    hi = bf16rne(x);
    lo = bf16rne(x - bf16tof(hi));
}

union FragU { uint4 u; short8v v; };

// ---- Prep: split W2 into bf16 hi/lo MFMA B-fragments in d_ws ----
// lane = s + 16*g holds k = 32*kt + 8*g + j, column nb*16 + s.
__global__ __launch_bounds__(64)
void prep_w2(const float* __restrict__ W2a, const float* __restrict__ W2b,
             unsigned short* __restrict__ frag)
{
    const int lane = threadIdx.x;
    const int nb = blockIdx.x, kt = blockIdx.y, pipe = blockIdx.z;
    const float* __restrict__ W2 = pipe ? W2b : W2a;
    const int g = lane >> 4, s = lane & 15;
    unsigned ph[4], pl[4];
    #pragma unroll
    for (int p = 0; p < 4; ++p) {
        const float x0 = W2[(size_t)(32*kt + 8*g + 2*p)     * WN + nb*16 + s];
        const float x1 = W2[(size_t)(32*kt + 8*g + 2*p + 1) * WN + nb*16 + s];
        unsigned h0, l0, h1, l1;
        bf16split(x0, h0, l0);
        bf16split(x1, h1, l1);
        ph[p] = h0 | (h1 << 16);
        pl[p] = l0 | (l1 << 16);
    }
    const size_t fi = (size_t)pipe * 32768 + (size_t)((kt*16 + nb)*64 + lane) * 8;
    *(uint4*)(frag + fi)                  = make_uint4(ph[0], ph[1], ph[2], ph[3]);
    *(uint4*)(frag + FRAG_HI_SHORTS + fi) = make_uint4(pl[0], pl[1], pl[2], pl[3]);
}

// ---- Prep: split W1 into bf16 hi/lo MFMA B-fragments (same convention) ----
__global__ __launch_bounds__(64)
void prep_w1(const float* __restrict__ W1a, const float* __restrict__ W1b,
             unsigned short* __restrict__ frag)
{
    const int lane = threadIdx.x;
    const int nb = blockIdx.x, kt = blockIdx.y, pipe = blockIdx.z;
    const float* __restrict__ W1 = pipe ? W1b : W1a;
    const int g = lane >> 4, s = lane & 15;
    unsigned ph[4], pl[4];
    #pragma unroll
    for (int p = 0; p < 4; ++p) {
        const float x0 = W1[(size_t)(32*kt + 8*g + 2*p)     * HID + nb*16 + s];
        const float x1 = W1[(size_t)(32*kt + 8*g + 2*p + 1) * HID + nb*16 + s];
        unsigned h0, l0, h1, l1;
        bf16split(x0, h0, l0);
        bf16split(x1, h1, l1);
        ph[p] = h0 | (h1 << 16);
        pl[p] = l0 | (l1 << 16);
    }
    const size_t fi = (size_t)W1HI + (size_t)pipe * 8192
                    + (size_t)((kt*8 + nb)*64 + lane) * 8;
    *(uint4*)(frag + fi)              = make_uint4(ph[0], ph[1], ph[2], ph[3]);
    *(uint4*)(frag + W1LO_DELTA + fi) = make_uint4(pl[0], pl[1], pl[2], pl[3]);
}

__global__ __launch_bounds__(NT, 4)
void fused_mlp_dtp(
    const float* __restrict__ fea_a, const float* __restrict__ vec_a,
    const float* __restrict__ len_a, const float* __restrict__ b1_a,
    const float* __restrict__ g_a,   const float* __restrict__ be_a,
    const float* __restrict__ fea_b, const float* __restrict__ vec_b,
    const float* __restrict__ len_b, const float* __restrict__ b1_b,
    const float* __restrict__ g_b,   const float* __restrict__ be_b,
    const unsigned short* __restrict__ fragW,
    float* __restrict__ out)
{
    // Time-aliased LDS (33792 B): len[64][68] -> act[64][132] -> epi stage
    __shared__ __align__(16) float smem[SMEMF];

    const int pipe = blockIdx.y;
    const float* __restrict__ fea = pipe ? fea_b : fea_a;
    const float* __restrict__ vec = pipe ? vec_b : vec_a;
    const float* __restrict__ len = pipe ? len_b : len_a;
    const float* __restrict__ b1  = pipe ? b1_b  : b1_a;
    const float* __restrict__ g   = pipe ? g_b   : g_a;
    const float* __restrict__ be  = pipe ? be_b  : be_a;
    float* __restrict__ outp = out + (size_t)pipe * (size_t)E_N * FEA;

    const int t    = threadIdx.x;
    const int lane = t & 63;
    const int wv_  = t >> 6;
    const int s_   = lane & 15, g_ = lane >> 4;
    const long e0  = (long)blockIdx.x * EPB;

    // ---------- Phase 1: stage len tile [64][68] ----------
    {
        const float4* __restrict__ src = (const float4*)(len + e0 * RAD);
        #pragma unroll
        for (int i = 0; i < (EPB * RAD / 4) / NT; ++i) {
            const int f = t + i * NT;            // 0..1023
            const float4 v = src[f];
            const int e = f >> 4, kq = (f & 15) * 4;
            *(float4*)(&smem[e * LSTR + kq]) = v;
        }
    }
    __syncthreads();

    // ---------- Phase 2: h = len @ W1 via split-bf16 MFMA ----------
    // Wave owns edges [16w,16w+16); acc2[nb] covers cols [16nb,16nb+16).
    floatx4 acc2[8];
    #pragma unroll
    for (int nb = 0; nb < 8; ++nb) {
        acc2[nb][0] = 0.f; acc2[nb][1] = 0.f; acc2[nb][2] = 0.f; acc2[nb][3] = 0.f;
    }
    {
        const int eA = wv_ * 16 + s_;
        const unsigned short* __restrict__ fH1 = fragW + W1HI + (size_t)pipe * 8192;
        const unsigned short* __restrict__ fL1 = fH1 + W1LO_DELTA;
        #pragma unroll
        for (int kt = 0; kt < 2; ++kt) {
            float xs[8];
            {
                const float4 x0 = *(const float4*)(&smem[eA*LSTR + 32*kt + 8*g_]);
                const float4 x1 = *(const float4*)(&smem[eA*LSTR + 32*kt + 8*g_ + 4]);
                xs[0]=x0.x; xs[1]=x0.y; xs[2]=x0.z; xs[3]=x0.w;
                xs[4]=x1.x; xs[5]=x1.y; xs[6]=x1.z; xs[7]=x1.w;
            }
            FragU ahu, alu;
            {
                unsigned ph[4], pl[4];
                #pragma unroll
                for (int p = 0; p < 4; ++p) {
                    unsigned h0, l0, h1, l1;
                    bf16split(xs[2*p],     h0, l0);
                    bf16split(xs[2*p + 1], h1, l1);
                    ph[p] = h0 | (h1 << 16);
                    pl[p] = l0 | (l1 << 16);
                }
                ahu.u = make_uint4(ph[0], ph[1], ph[2], ph[3]);
                alu.u = make_uint4(pl[0], pl[1], pl[2], pl[3]);
            }
            const short8v ah = ahu.v, al = alu.v;
            const size_t kb = (size_t)(kt * 8) * 512 + (size_t)lane * 8;
            #pragma unroll
            for (int nb = 0; nb < 8; ++nb) {
                const short8v bh = *(const short8v*)(fH1 + kb + nb * 512);
                const short8v bl = *(const short8v*)(fL1 + kb + nb * 512);
                acc2[nb] = __builtin_amdgcn_mfma_f32_16x16x32_bf16(ah, bh, acc2[nb], 0, 0, 0);
                acc2[nb] = __builtin_amdgcn_mfma_f32_16x16x32_bf16(ah, bl, acc2[nb], 0, 0, 0);
                acc2[nb] = __builtin_amdgcn_mfma_f32_16x16x32_bf16(al, bh, acc2[nb], 0, 0, 0);
            }
        }
    }
    __syncthreads();   // len reads complete; region becomes act

    // ---------- Phase 3: b1 + LayerNorm + SiLU in REGISTERS, scatter act ----
    // C-layout: acc2[nb][r] = h[edge wv*16+4g_+r][col 16nb+s_].
    // Row reduce = in-lane over nb + shfl_xor(1,2,4,8) over the s_ group.
    {
        float hv[8][4];
        float sum[4] = {0.f, 0.f, 0.f, 0.f};
        float sq [4] = {0.f, 0.f, 0.f, 0.f};
        #pragma unroll
        for (int nb = 0; nb < 8; ++nb) {
            const float b1v = b1[16*nb + s_];
            #pragma unroll
            for (int r = 0; r < 4; ++r) {
                const float v = acc2[nb][r] + b1v;
                hv[nb][r] = v;
                sum[r] += v;
                sq [r] += v * v;
            }
        }
        float mu[4], iv[4];
        #pragma unroll
        for (int r = 0; r < 4; ++r) {
            float s1 = sum[r], s2 = sq[r];
            s1 += __shfl_xor(s1, 1); s1 += __shfl_xor(s1, 2);
            s1 += __shfl_xor(s1, 4); s1 += __shfl_xor(s1, 8);
            s2 += __shfl_xor(s2, 1); s2 += __shfl_xor(s2, 2);
            s2 += __shfl_xor(s2, 4); s2 += __shfl_xor(s2, 8);
            mu[r] = s1 * (1.0f / HID);
            float var = s2 * (1.0f / HID) - mu[r] * mu[r];
            var = fmaxf(var, 0.0f);
            iv[r] = rsqrtf(var + 1e-5f);
        }
        const int rowb = wv_ * 16 + 4 * g_;
        #pragma unroll
        for (int nb = 0; nb < 8; ++nb) {
            const float gv  = g [16*nb + s_];
            const float bev = be[16*nb + s_];
            #pragma unroll
            for (int r = 0; r < 4; ++r) {
                const float hn = (hv[nb][r] - mu[r]) * iv[r] * gv + bev;
                const float sl = hn / (1.0f + __expf(-hn));
                smem[(rowb + r) * ASTR + 16*nb + s_] = sl;   // 2-way, free
            }
        }
    }
    __syncthreads();

    // ---------- Phase 4: w = silu @ W2 via split-bf16 MFMA (proven r13) -----
    floatx4 acc[16];
    #pragma unroll
    for (int nb = 0; nb < 16; ++nb) {
        acc[nb][0] = 0.f; acc[nb][1] = 0.f; acc[nb][2] = 0.f; acc[nb][3] = 0.f;
    }
    {
        const int eA = wv_ * 16 + s_;
        const unsigned short* __restrict__ fH = fragW + (size_t)pipe * 32768;
        const unsigned short* __restrict__ fL = fH + FRAG_HI_SHORTS;
        for (int kt = 0; kt < 4; ++kt) {
            float xs[8];
            {
                const float4 x0 = *(const float4*)(&smem[eA*ASTR + 32*kt + 8*g_]);
                const float4 x1 = *(const float4*)(&smem[eA*ASTR + 32*kt + 8*g_ + 4]);
                xs[0]=x0.x; xs[1]=x0.y; xs[2]=x0.z; xs[3]=x0.w;
                xs[4]=x1.x; xs[5]=x1.y; xs[6]=x1.z; xs[7]=x1.w;
            }
            FragU ahu, alu;
            {
                unsigned ph[4], pl[4];
                #pragma unroll
                for (int p = 0; p < 4; ++p) {
                    unsigned h0, l0, h1, l1;
                    bf16split(xs[2*p],     h0, l0);
                    bf16split(xs[2*p + 1], h1, l1);
                    ph[p] = h0 | (h1 << 16);
                    pl[p] = l0 | (l1 << 16);
                }
                ahu.u = make_uint4(ph[0], ph[1], ph[2], ph[3]);
                alu.u = make_uint4(pl[0], pl[1], pl[2], pl[3]);
            }
            const short8v ah = ahu.v, al = alu.v;
            const size_t kb = (size_t)(kt * 16) * 512 + (size_t)lane * 8;
            #pragma unroll
            for (int nb = 0; nb < 16; ++nb) {
                const short8v bh = *(const short8v*)(fH + kb + nb * 512);
                const short8v bl = *(const short8v*)(fL + kb + nb * 512);
                acc[nb] = __builtin_amdgcn_mfma_f32_16x16x32_bf16(ah, bh, acc[nb], 0, 0, 0);
                acc[nb] = __builtin_amdgcn_mfma_f32_16x16x32_bf16(ah, bl, acc[nb], 0, 0, 0);
                acc[nb] = __builtin_amdgcn_mfma_f32_16x16x32_bf16(al, bh, acc[nb], 0, 0, 0);
            }
        }
    }
    __syncthreads();   // all act reads done; region becomes epilogue stage

    // ---------- Epilogue: DTP from C-layout (proven r13) ----------
    {
        const float c2 = 0.70710678118654752f;   // 1/sqrt(2)
        const float c3 = 0.40824829046386302f;   // 1/sqrt(6)
        float* sStage = smem + wv_ * 784;        // [4 rows][196], per-wave
        for (int r = 0; r < 4; ++r) {
            const long e = e0 + wv_ * 16 + 4 * g_ + r;
            const float4 y = *(const float4*)(vec + e * 4);
            const float* __restrict__ fr   = fea  + e * (size_t)FEA;
            float* __restrict__       orow = outp + e * (size_t)FEA;
            #pragma unroll
            for (int q = 0; q < 4; ++q) {
                const int u = 16 * q + s_;
                const float w1 = acc[q     ][r];
                const float w2 = acc[q + 4 ][r];
                const float w3 = acc[q + 8 ][r];
                const float w4 = acc[q + 12][r];
                const float x0  = fr[u];
                const float x1a = fr[64 + 3*u + 0];
                const float x1b = fr[64 + 3*u + 1];
                const float x1c = fr[64 + 3*u + 2];
                const float dot = x1a*y.y + x1b*y.z + x1c*y.w;
                orow[u] = w1*x0*y.x*c2 + w4*dot*c3;
                sStage[g_*196 + 3*u + 0] = (w2*x0*y.y + w3*x1a*y.x) * c2;
                sStage[g_*196 + 3*u + 1] = (w2*x0*y.z + w3*x1b*y.x) * c2;
                sStage[g_*196 + 3*u + 2] = (w2*x0*y.w + w3*x1c*y.x) * c2;
            }
            __syncthreads();   // stage complete (convergent: all waves, all r)
            #pragma unroll
            for (int rr = 0; rr < 3; ++rr) {
                const int flat = rr * 256 + lane * 4;     // 0..764
                const int eloc = flat / 192;              // 0..3 (g-group)
                const int pos  = flat % 192;              // 16B aligned
                const float4 v = *(const float4*)(&sStage[eloc * 196 + pos]);
                *(float4*)(&outp[(e0 + wv_*16 + 4*eloc + r) * (size_t)FEA + 64 + pos]) = v;
            }
            __syncthreads();   // drain complete before next r overwrites
        }
    }
}

extern "C" void kernel_launch(void* const* d_in, const int* in_sizes, int n_in,
                              void* d_out, int out_size, void* d_ws, size_t ws_size,
                              hipStream_t stream) {
    (void)in_sizes; (void)n_in; (void)ws_size; (void)out_size;
    const float* fea_a = (const float*)d_in[0];
    const float* vec_a = (const float*)d_in[1];
    const float* len_a = (const float*)d_in[2];
    const float* W1_a  = (const float*)d_in[3];
    const float* b1_a  = (const float*)d_in[4];
    const float* g_a   = (const float*)d_in[5];
    const float* be_a  = (const float*)d_in[6];
    const float* W2_a  = (const float*)d_in[7];
    const float* fea_b = (const float*)d_in[8];
    const float* vec_b = (const float*)d_in[9];
    const float* len_b = (const float*)d_in[10];
    const float* W1_b  = (const float*)d_in[11];
    const float* b1_b  = (const float*)d_in[12];
    const float* g_b   = (const float*)d_in[13];
    const float* be_b  = (const float*)d_in[14];
    const float* W2_b  = (const float*)d_in[15];
    float* out = (float*)d_out;
    unsigned short* frag = (unsigned short*)d_ws;   // needs 320 KB

    hipLaunchKernelGGL(prep_w2, dim3(16, 4, 2), dim3(64), 0, stream,
                       W2_a, W2_b, frag);
    hipLaunchKernelGGL(prep_w1, dim3(8, 2, 2), dim3(64), 0, stream,
                       W1_a, W1_b, frag);

    dim3 grid(E_N / EPB, 2);
    dim3 block(NT);
    hipLaunchKernelGGL(fused_mlp_dtp, grid, block, 0, stream,
                       fea_a, vec_a, len_a, b1_a, g_a, be_a,
                       fea_b, vec_b, len_b, b1_b, g_b, be_b,
                       frag, out);
}